// Round 3
// baseline (1436.121 us; speedup 1.0000x reference)
//
#include <hip/hip_runtime.h>
#include <stdint.h>

// Problem constants (from reference)
#define NB 16
#define NP 16384
#define NC 76
#define KSEL 1024
#define KOUT 256

// ---------------------------------------------------------------------------
// Kernel 1: per-batch top-1024 selection (radix select on composite key),
// rank-by-counting ordering, decode, BEV box computation.
// One block (1024 thr) per batch.
// ---------------------------------------------------------------------------
__global__ __launch_bounds__(1024, 1) void k_select_decode(
    const float* __restrict__ scores,   // [B][N]
    const float* __restrict__ reg,      // [B][N][76]
    const float* __restrict__ xyz,      // [B][N][3]
    const float* __restrict__ msz,      // [3]
    float* __restrict__ props,          // [B][1024][8] (7 used)
    float* __restrict__ bev,            // [B][1024][4]
    float* __restrict__ selsc)          // [B][1024]
{
    const int b = blockIdx.x;
    const int t = threadIdx.x;
    const int lane = t & 63;
    const int wave = t >> 6;

    const float* sb = scores + (size_t)b * NP;

    // Load 16 keys/thread. Composite key:
    // (mangled_score << 14) | (16383 - idx) -> all distinct, stable ordering
    // identical to jnp.argsort(-scores) (ties -> smaller idx first).
    uint64_t key[16];
#pragma unroll
    for (int k = 0; k < 16; ++k) {
        int i = (k << 10) | t;
        uint32_t u = __float_as_uint(sb[i]);
        u ^= (u & 0x80000000u) ? 0xFFFFFFFFu : 0x80000000u;
        key[k] = ((uint64_t)u << 14) | (uint64_t)(16383 - i);
    }

    __shared__ unsigned int hist[16][256];   // per-wave histograms
    __shared__ unsigned int sS[256];         // inclusive suffix sums
    __shared__ unsigned int wtot[4];
    __shared__ uint64_t sh_prefix;
    __shared__ unsigned int sh_remaining;
    __shared__ uint64_t sel[1024];
    __shared__ unsigned int selcnt;
    if (t == 0) { sh_prefix = 0ull; sh_remaining = KSEL; selcnt = 0u; }

    uint64_t prefix = 0ull;
    for (int pass = 0; pass < 6; ++pass) {
        const int shift = 40 - 8 * pass;
        // zero histograms (4 words per thread)
        for (int q = t; q < 16 * 256; q += 1024) ((unsigned int*)hist)[q] = 0u;
        __syncthreads();
#pragma unroll
        for (int k = 0; k < 16; ++k) {
            uint64_t kk = key[k];
            if ((kk >> (shift + 8)) == (prefix >> (shift + 8)))
                atomicAdd(&hist[wave][(unsigned)((kk >> shift) & 255ull)], 1u);
        }
        __syncthreads();
        // reduce 16 copies + intra-wave inclusive suffix sum (threads 0..255)
        unsigned int v = 0;
        if (t < 256) {
            unsigned int s = 0;
#pragma unroll
            for (int w = 0; w < 16; ++w) s += hist[w][t];
            v = s;
#pragma unroll
            for (int o = 1; o < 64; o <<= 1) {
                unsigned int u = __shfl_down(v, o);
                v += (lane + o < 64) ? u : 0u;
            }
            if (lane == 0) wtot[wave] = v;   // wave total (suffix @ lane 0)
        }
        __syncthreads();
        if (t < 256) {
            unsigned int add = 0;
#pragma unroll
            for (int q = 0; q < 4; ++q) if (q > wave) add += wtot[q];
            sS[t] = v + add;                 // S[t] = sum_{d>=t} count[d]
        }
        __syncthreads();
        if (t < 256) {
            unsigned int rem = sh_remaining;
            bool p  = sS[t] >= rem;
            bool pn = (t < 255) && (sS[t + 1] >= rem);
            if (p && !pn) {                  // largest digit with S >= rem
                sh_prefix |= ((uint64_t)t) << shift;
                sh_remaining = rem - ((t < 255) ? sS[t + 1] : 0u);
            }
        }
        __syncthreads();
        prefix = sh_prefix;
    }
    const uint64_t T = prefix;   // exact 1024th-largest key (all keys distinct)

    // compact the exactly-1024 winners (wave-aggregated atomics)
#pragma unroll
    for (int k = 0; k < 16; ++k) {
        bool p = key[k] >= T;
        unsigned long long m = __ballot(p);
        if (m) {
            unsigned int base;
            if (lane == 0) base = atomicAdd(&selcnt, (unsigned)__popcll(m));
            base = __shfl(base, 0);
            if (p) sel[base + (unsigned)__popcll(m & ((1ull << lane) - 1ull))] = key[k];
        }
    }
    __syncthreads();

    // rank by counting (LDS broadcast reads, conflict-free, no barriers)
    const uint64_t kk = sel[t];
    int rank = 0;
#pragma unroll 16
    for (int j = 0; j < 1024; ++j) rank += (sel[j] > kk) ? 1 : 0;

    // decode: this thread's key has rank `rank`
    const int idx = 16383 - (int)(kk & 16383ull);
    const float sc = sb[idx];
    const float* rr = reg + ((size_t)b * NP + idx) * NC;
    const float* xr = xyz + ((size_t)b * NP + idx) * 3;
    const float4* rr4 = (const float4*)rr;   // rows are 16B-aligned (76*4=304)

    float4 R0 = rr4[0], R1 = rr4[1], R2 = rr4[2];       // x bins 0..11
    float4 R3 = rr4[3], R4 = rr4[4], R5 = rr4[5];       // z bins 12..23
    float4 R12 = rr4[12], R13 = rr4[13], R14 = rr4[14]; // 48..59
    float r60 = rr[60];
    float4 R18 = rr4[18];                               // 72..75

    float best; int bj;
    {
        const float vx[12] = {R0.x,R0.y,R0.z,R0.w,R1.x,R1.y,R1.z,R1.w,R2.x,R2.y,R2.z,R2.w};
        best = vx[0]; bj = 0;
#pragma unroll
        for (int j = 1; j < 12; ++j) if (vx[j] > best) { best = vx[j]; bj = j; }
    }
    const int xbin = bj;
    {
        const float vz[12] = {R3.x,R3.y,R3.z,R3.w,R4.x,R4.y,R4.z,R4.w,R5.x,R5.y,R5.z,R5.w};
        best = vz[0]; bj = 0;
#pragma unroll
        for (int j = 1; j < 12; ++j) if (vz[j] > best) { best = vz[j]; bj = j; }
    }
    const int zbin = bj;
    {
        const float vr[12] = {R12.y,R12.z,R12.w,R13.x,R13.y,R13.z,R13.w,R14.x,R14.y,R14.z,R14.w,r60};
        best = vr[0]; bj = 0;
#pragma unroll
        for (int j = 1; j < 12; ++j) if (vr[j] > best) { best = vr[j]; bj = j; }
    }
    const int rybin = bj;

    const float xres = rr[24 + xbin];    // dynamic gathers stay in global
    const float zres = rr[36 + zbin];
    const float ryres = rr[61 + rybin];

    float posx = ((float)xbin * 0.5f + 0.25f - 3.0f) + xres * 0.5f;
    float posz = ((float)zbin * 0.5f + 0.25f - 3.0f) + zres * 0.5f;
    float posy = xr[1] + R12.x;          // rr[48]

    const float apc   = 0.5235987755982988f;   // 2*pi/12
    const float apch  = 0.2617993877991494f;   // apc/2
    const float twopi = 6.283185307179586f;
    const float fpi   = 3.141592653589793f;
    float ry = (float)rybin * apc + ryres * apch;
    ry = fmodf(ry, twopi);
    if (ry < 0.f) ry += twopi;
    if (ry > fpi) ry -= twopi;

    const float a0 = msz[0], a1 = msz[1], a2 = msz[2];
    const float h = R18.y * a0 + a0;     // rr[73..75]
    const float w = R18.z * a1 + a1;
    const float l = R18.w * a2 + a2;
    posx += xr[0];
    posz += xr[2];
    posy += h * 0.5f;                    // props[:,1] += h/2

    const size_t o = ((size_t)b << 10) | (size_t)rank;
    float* pp = props + o * 8;
    pp[0] = posx; pp[1] = posy; pp[2] = posz; pp[3] = h; pp[4] = w; pp[5] = l; pp[6] = ry;
    const float hl = l * 0.5f, hw = w * 0.5f;
    float* bb = bev + o * 4;
    bb[0] = posx - hl; bb[1] = posz - hw; bb[2] = posx + hl; bb[3] = posz + hw;
    selsc[o] = sc;
}

// ---------------------------------------------------------------------------
// Kernel 2: mark rows that suppress anything (loose threshold -> superset,
// exact decision recomputed in kernel 3). One block per (batch, 64-row word):
// NB*16 = 256 blocks x 512 threads. Wave w scans a 128-wide j window;
// lane = row within the word. Divide-free IoU test.
// ---------------------------------------------------------------------------
__global__ __launch_bounds__(512) void k_overlap_flags(
    const float* __restrict__ bev,
    unsigned long long* __restrict__ rowNZ)
{
    const int b  = blockIdx.x >> 4;
    const int ic = blockIdx.x & 15;      // i-word index (rows ic*64 .. ic*64+63)
    const int t = threadIdx.x;
    const int lane = t & 63;
    const int wv = t >> 6;               // 0..7 -> j window [wv*128, wv*128+128)

    __shared__ float4 sbev[1024];
    __shared__ float sta[1024];          // T*area (+T*eps folded at use)
    __shared__ unsigned long long sword;
    if (t == 0) sword = 0ull;

    const float4* gb = (const float4*)(bev + (((size_t)b << 10) * 4));
    for (int i = t; i < 1024; i += 512) {
        float4 v = gb[i];
        sbev[i] = v;
        sta[i] = 0.8495f * ((v.z - v.x) * (v.w - v.y));
    }
    __syncthreads();

    const int i = (ic << 6) + lane;
    const float4 bi = sbev[i];
    const float tai = sta[i] + 0.8495e-8f;   // T*ai + T*eps

    bool any = false;
    const int j0 = wv << 7;
    if (j0 + 127 > i) {                  // wave-uniform skip for windows below i-word
#pragma unroll 4
        for (int j = j0; j < j0 + 128; ++j) {
            float4 bj = sbev[j];
            float ltx = fmaxf(bi.x, bj.x), lty = fmaxf(bi.y, bj.y);
            float rbx = fminf(bi.z, bj.z), rby = fminf(bi.w, bj.w);
            float w0 = fmaxf(rbx - ltx, 0.f), h0 = fmaxf(rby - lty, 0.f);
            float inter = w0 * h0;
            // iou > T  <=>  inter*(1+T) > T*ai + T*aj + T*eps
            any |= (j > i) & (inter * 1.8495f > tai + sta[j]);
        }
    }
    unsigned long long m = __ballot(any);
    if (lane == 0 && m) atomicOr(&sword, m);
    __syncthreads();
    if (t == 0) rowNZ[b * 16 + ic] = sword;   // sole owner of this word
}

// ---------------------------------------------------------------------------
// Kernel 3: greedy NMS propagation (word-blocked; exact 0.85 threshold,
// rows rebuilt on demand via ballots) + output scatter. 1 block per batch.
// ---------------------------------------------------------------------------
__global__ __launch_bounds__(256) void k_nms_out(
    const unsigned long long* __restrict__ rowNZ,
    const float* __restrict__ bev,
    const float* __restrict__ props,
    const float* __restrict__ selsc,
    float* __restrict__ out)
{
    const int b = blockIdx.x;
    const int t = threadIdx.x;
    __shared__ float4 sbev[1024];
    __shared__ float sarea[1024];
    __shared__ unsigned long long keepW[16];
    __shared__ int wbase[16];
    __shared__ int sh_n;

    const float4* gb = (const float4*)(bev + (((size_t)b << 10) * 4));
    for (int i = t; i < 1024; i += 256) {
        float4 v = gb[i];
        sbev[i] = v;
        sarea[i] = (v.z - v.x) * (v.w - v.y);
    }
    __syncthreads();

    if (t < 64) {           // wave 0 does the (mostly trivial) serial pass
        const int lane = t;
        unsigned long long remv = 0ull;
        unsigned long long summ = (lane < 16) ? rowNZ[b * 16 + lane] : 0ull;
        for (int w = 0; w < 16; ++w) {
            unsigned long long rw = __shfl(remv, w);
            unsigned long long nz = __shfl(summ, w);
            unsigned long long keepw = ~rw;
            unsigned long long cand = nz & keepw;
            while (cand) {
                int bidx = __ffsll((long long)cand) - 1;
                cand &= cand - 1ull;
                if ((keepw >> bidx) & 1ull) {
                    const int i = (w << 6) + bidx;
                    const float4 bi = sbev[i];
                    const float ai = sarea[i];
                    unsigned long long row = 0ull;
#pragma unroll
                    for (int c = 0; c < 16; ++c) {
                        int j = (c << 6) + lane;
                        bool sup = false;
                        if (j > i) {
                            float4 bj = sbev[j];
                            float ltx = fmaxf(bi.x, bj.x), lty = fmaxf(bi.y, bj.y);
                            float rbx = fminf(bi.z, bj.z), rby = fminf(bi.w, bj.w);
                            float w0 = fmaxf(rbx - ltx, 0.f), h0 = fmaxf(rby - lty, 0.f);
                            float inter = w0 * h0;
                            float iou = inter / (ai + sarea[j] - inter + 1e-8f);
                            sup = iou > 0.85f;
                        }
                        unsigned long long word = __ballot(sup);
                        if (lane == c) row = word;
                    }
                    remv |= row;
                    unsigned long long roww = __shfl(row, w);
                    keepw &= ~roww;
                    cand  &= ~roww;
                }
            }
            if (lane == 0) keepW[w] = keepw;
        }
    }
    __syncthreads();

    if (t < 16) wbase[t] = (int)__popcll(keepW[t]);
    __syncthreads();
    if (t == 0) {
        int acc = 0;
        for (int w = 0; w < 16; ++w) { int c = wbase[w]; wbase[w] = acc; acc += c; }
        sh_n = acc;
    }
    __syncthreads();

    const int nk = sh_n;
    const int n = nk < KOUT ? nk : KOUT;
    const float* pb = props + (((size_t)b << 10) * 8);
    const float* scb = selsc + ((size_t)b << 10);
    float* ob = out + (size_t)b * KOUT * 7;
    float* os = out + (size_t)NB * KOUT * 7 + (size_t)b * KOUT;

    for (int i = t; i < 1024; i += 256) {
        const int w = i >> 6, bit = i & 63;
        unsigned long long kw = keepW[w];
        if ((kw >> bit) & 1ull) {
            int r = wbase[w] + (int)__popcll(kw & ((1ull << bit) - 1ull));
            if (r < KOUT) {
#pragma unroll
                for (int c = 0; c < 7; ++c) ob[r * 7 + c] = pb[i * 8 + c];
                os[r] = scb[i];
            }
        }
    }
    // zero unfilled slots (harness poisons d_out)
    {
        int r = t;
        if (r < KOUT && r >= n) {
#pragma unroll
            for (int c = 0; c < 7; ++c) ob[r * 7 + c] = 0.f;
            os[r] = 0.f;
        }
    }
}

// ---------------------------------------------------------------------------
extern "C" void kernel_launch(void* const* d_in, const int* in_sizes, int n_in,
                              void* d_out, int out_size, void* d_ws, size_t ws_size,
                              hipStream_t stream) {
    const float* scores = (const float*)d_in[0];
    const float* reg    = (const float*)d_in[1];
    const float* xyz    = (const float*)d_in[2];
    const float* msz    = (const float*)d_in[3];
    float* out = (float*)d_out;

    char* ws = (char*)d_ws;
    float* props = (float*)ws;                                    // 16*1024*8*4 = 512 KiB
    float* bev   = (float*)(ws + 524288);                         // 16*1024*4*4 = 256 KiB
    float* selsc = (float*)(ws + 524288 + 262144);                // 16*1024*4   =  64 KiB
    unsigned long long* rowNZ =
        (unsigned long long*)(ws + 524288 + 262144 + 65536);      // 16*16*8     =   2 KiB

    k_select_decode<<<dim3(NB), dim3(1024), 0, stream>>>(scores, reg, xyz, msz,
                                                         props, bev, selsc);
    k_overlap_flags<<<dim3(NB * 16), dim3(512), 0, stream>>>(bev, rowNZ);
    k_nms_out<<<dim3(NB), dim3(256), 0, stream>>>(rowNZ, bev, props, selsc, out);
}

// Round 4
// 63.026 us; speedup vs baseline: 22.7860x; 22.7860x over previous
//
#include <hip/hip_runtime.h>
#include <stdint.h>

// Problem constants (from reference)
#define NB 16
#define NP 16384
#define NC 76
#define KSEL 1024
#define KOUT 256

// ---------------------------------------------------------------------------
// Kernel 1: per-batch top-1024 selection (radix select on composite key),
// rank-by-counting ordering, decode, BEV box computation.
// One block (1024 thr) per batch.
// ---------------------------------------------------------------------------
__global__ __launch_bounds__(1024, 1) void k_select_decode(
    const float* __restrict__ scores,   // [B][N]
    const float* __restrict__ reg,      // [B][N][76]
    const float* __restrict__ xyz,      // [B][N][3]
    const float* __restrict__ msz,      // [3]
    float* __restrict__ props,          // [B][1024][8] (7 used)
    float* __restrict__ bev,            // [B][1024][4]
    float* __restrict__ selsc)          // [B][1024]
{
    const int b = blockIdx.x;
    const int t = threadIdx.x;
    const int lane = t & 63;
    const int wave = t >> 6;

    const float* sb = scores + (size_t)b * NP;

    // Load 16 keys/thread. Composite key:
    // (mangled_score << 14) | (16383 - idx) -> all distinct, stable ordering
    // identical to jnp.argsort(-scores) (ties -> smaller idx first).
    uint64_t key[16];
#pragma unroll
    for (int k = 0; k < 16; ++k) {
        int i = (k << 10) | t;
        uint32_t u = __float_as_uint(sb[i]);
        u ^= (u & 0x80000000u) ? 0xFFFFFFFFu : 0x80000000u;
        key[k] = ((uint64_t)u << 14) | (uint64_t)(16383 - i);
    }

    __shared__ unsigned int hist[16][256];   // per-wave histograms
    __shared__ unsigned int sS[256];         // inclusive suffix sums
    __shared__ unsigned int wtot[4];
    __shared__ uint64_t sh_prefix;
    __shared__ unsigned int sh_remaining;
    __shared__ uint64_t sel[1024];
    __shared__ unsigned int selcnt;
    if (t == 0) { sh_prefix = 0ull; sh_remaining = KSEL; selcnt = 0u; }

    uint64_t prefix = 0ull;
    for (int pass = 0; pass < 6; ++pass) {
        const int shift = 40 - 8 * pass;
        // zero histograms (4 words per thread)
        for (int q = t; q < 16 * 256; q += 1024) ((unsigned int*)hist)[q] = 0u;
        __syncthreads();
#pragma unroll
        for (int k = 0; k < 16; ++k) {
            uint64_t kk = key[k];
            if ((kk >> (shift + 8)) == (prefix >> (shift + 8)))
                atomicAdd(&hist[wave][(unsigned)((kk >> shift) & 255ull)], 1u);
        }
        __syncthreads();
        // reduce 16 copies + intra-wave inclusive suffix sum (threads 0..255)
        unsigned int v = 0;
        if (t < 256) {
            unsigned int s = 0;
#pragma unroll
            for (int w = 0; w < 16; ++w) s += hist[w][t];
            v = s;
#pragma unroll
            for (int o = 1; o < 64; o <<= 1) {
                unsigned int u = __shfl_down(v, o);
                v += (lane + o < 64) ? u : 0u;
            }
            if (lane == 0) wtot[wave] = v;   // wave total (suffix @ lane 0)
        }
        __syncthreads();
        if (t < 256) {
            unsigned int add = 0;
#pragma unroll
            for (int q = 0; q < 4; ++q) if (q > wave) add += wtot[q];
            sS[t] = v + add;                 // S[t] = sum_{d>=t} count[d]
        }
        __syncthreads();
        if (t < 256) {
            unsigned int rem = sh_remaining;
            bool p  = sS[t] >= rem;
            bool pn = (t < 255) && (sS[t + 1] >= rem);
            if (p && !pn) {                  // largest digit with S >= rem
                sh_prefix |= ((uint64_t)t) << shift;
                sh_remaining = rem - ((t < 255) ? sS[t + 1] : 0u);
            }
        }
        __syncthreads();
        prefix = sh_prefix;
    }
    const uint64_t T = prefix;   // exact 1024th-largest key (all keys distinct)

    // compact the exactly-1024 winners (wave-aggregated atomics)
#pragma unroll
    for (int k = 0; k < 16; ++k) {
        bool p = key[k] >= T;
        unsigned long long m = __ballot(p);
        if (m) {
            unsigned int base;
            if (lane == 0) base = atomicAdd(&selcnt, (unsigned)__popcll(m));
            base = __shfl(base, 0);
            if (p) sel[base + (unsigned)__popcll(m & ((1ull << lane) - 1ull))] = key[k];
        }
    }
    __syncthreads();

    // rank by counting (LDS broadcast reads, conflict-free, no barriers)
    const uint64_t kk = sel[t];
    int rank = 0;
#pragma unroll 16
    for (int j = 0; j < 1024; ++j) rank += (sel[j] > kk) ? 1 : 0;

    // decode: this thread's key has rank `rank`
    const int idx = 16383 - (int)(kk & 16383ull);
    const float sc = sb[idx];
    const float* rr = reg + ((size_t)b * NP + idx) * NC;
    const float* xr = xyz + ((size_t)b * NP + idx) * 3;
    const float4* rr4 = (const float4*)rr;   // rows are 16B-aligned (76*4=304)

    float4 R0 = rr4[0], R1 = rr4[1], R2 = rr4[2];       // x bins 0..11
    float4 R3 = rr4[3], R4 = rr4[4], R5 = rr4[5];       // z bins 12..23
    float4 R12 = rr4[12], R13 = rr4[13], R14 = rr4[14]; // 48..59
    float r60 = rr[60];
    float4 R18 = rr4[18];                               // 72..75

    float best; int bj;
    {
        const float vx[12] = {R0.x,R0.y,R0.z,R0.w,R1.x,R1.y,R1.z,R1.w,R2.x,R2.y,R2.z,R2.w};
        best = vx[0]; bj = 0;
#pragma unroll
        for (int j = 1; j < 12; ++j) if (vx[j] > best) { best = vx[j]; bj = j; }
    }
    const int xbin = bj;
    {
        const float vz[12] = {R3.x,R3.y,R3.z,R3.w,R4.x,R4.y,R4.z,R4.w,R5.x,R5.y,R5.z,R5.w};
        best = vz[0]; bj = 0;
#pragma unroll
        for (int j = 1; j < 12; ++j) if (vz[j] > best) { best = vz[j]; bj = j; }
    }
    const int zbin = bj;
    {
        const float vr[12] = {R12.y,R12.z,R12.w,R13.x,R13.y,R13.z,R13.w,R14.x,R14.y,R14.z,R14.w,r60};
        best = vr[0]; bj = 0;
#pragma unroll
        for (int j = 1; j < 12; ++j) if (vr[j] > best) { best = vr[j]; bj = j; }
    }
    const int rybin = bj;

    const float xres = rr[24 + xbin];    // dynamic gathers stay in global
    const float zres = rr[36 + zbin];
    const float ryres = rr[61 + rybin];

    float posx = ((float)xbin * 0.5f + 0.25f - 3.0f) + xres * 0.5f;
    float posz = ((float)zbin * 0.5f + 0.25f - 3.0f) + zres * 0.5f;
    float posy = xr[1] + R12.x;          // rr[48]

    const float apc   = 0.5235987755982988f;   // 2*pi/12
    const float apch  = 0.2617993877991494f;   // apc/2
    const float twopi = 6.283185307179586f;
    const float fpi   = 3.141592653589793f;
    float ry = (float)rybin * apc + ryres * apch;
    ry = fmodf(ry, twopi);
    if (ry < 0.f) ry += twopi;
    if (ry > fpi) ry -= twopi;

    const float a0 = msz[0], a1 = msz[1], a2 = msz[2];
    const float h = R18.y * a0 + a0;     // rr[73..75]
    const float w = R18.z * a1 + a1;
    const float l = R18.w * a2 + a2;
    posx += xr[0];
    posz += xr[2];
    posy += h * 0.5f;                    // props[:,1] += h/2

    const size_t o = ((size_t)b << 10) | (size_t)rank;
    float* pp = props + o * 8;
    pp[0] = posx; pp[1] = posy; pp[2] = posz; pp[3] = h; pp[4] = w; pp[5] = l; pp[6] = ry;
    const float hl = l * 0.5f, hw = w * 0.5f;
    float* bb = bev + o * 4;
    bb[0] = posx - hl; bb[1] = posz - hw; bb[2] = posx + hl; bb[3] = posz + hw;
    selsc[o] = sc;
}

// ---------------------------------------------------------------------------
// Kernel 2: mark rows that suppress anything (loose threshold -> superset,
// exact decision recomputed in kernel 3). One block per (batch, 64-row word):
// NB*16 = 256 blocks x 512 threads. Wave w scans a 128-wide j window;
// lane = row within the word. Divide-free IoU test WITH sign guard:
//   iou > T  <=>  D > 0  &&  inter*(1+T) > T*(ai+aj+eps)   (D = ai+aj-inter+eps)
// The D>0 guard is essential: areas can be NEGATIVE (reg*anchor+anchor with
// reg ~ N(0,1)), and for D<=0 the reference iou = inter/D <= 0 never
// suppresses — an unguarded multiply-form flags those pairs spuriously
// (round-3 regression: K3's serial pass then rebuilt ~all rows, 1.4 ms).
// ---------------------------------------------------------------------------
__global__ __launch_bounds__(512) void k_overlap_flags(
    const float* __restrict__ bev,
    unsigned long long* __restrict__ rowNZ)
{
    const int b  = blockIdx.x >> 4;
    const int ic = blockIdx.x & 15;      // i-word index (rows ic*64 .. ic*64+63)
    const int t = threadIdx.x;
    const int lane = t & 63;
    const int wv = t >> 6;               // 0..7 -> j window [wv*128, wv*128+128)

    __shared__ float4 sbev[1024];
    __shared__ float sarea[1024];
    __shared__ unsigned long long sword;
    if (t == 0) sword = 0ull;

    const float4* gb = (const float4*)(bev + (((size_t)b << 10) * 4));
    for (int i = t; i < 1024; i += 512) {
        float4 v = gb[i];
        sbev[i] = v;
        sarea[i] = (v.z - v.x) * (v.w - v.y);
    }
    __syncthreads();

    const int i = (ic << 6) + lane;
    const float4 bi = sbev[i];
    const float aie = sarea[i] + 1e-8f;  // ai + eps

    bool any = false;
    const int j0 = wv << 7;
    if (j0 + 127 > i) {                  // wave-uniform skip for windows below i-word
#pragma unroll 4
        for (int j = j0; j < j0 + 128; ++j) {
            float4 bj = sbev[j];
            float ltx = fmaxf(bi.x, bj.x), lty = fmaxf(bi.y, bj.y);
            float rbx = fminf(bi.z, bj.z), rby = fminf(bi.w, bj.w);
            float w0 = fmaxf(rbx - ltx, 0.f), h0 = fmaxf(rby - lty, 0.f);
            float inter = w0 * h0;
            float sum = aie + sarea[j];          // ai + aj + eps
            // iou > 0.8495  <=>  (sum - inter > 0) && inter*1.8495 > 0.8495*sum
            any |= (j > i) & (sum > inter) & (inter * 1.8495f > 0.8495f * sum);
        }
    }
    unsigned long long m = __ballot(any);
    if (lane == 0 && m) atomicOr(&sword, m);
    __syncthreads();
    if (t == 0) rowNZ[b * 16 + ic] = sword;   // sole owner of this word
}

// ---------------------------------------------------------------------------
// Kernel 3: greedy NMS propagation (word-blocked; exact 0.85 threshold,
// rows rebuilt on demand via ballots) + output scatter. 1 block per batch.
// ---------------------------------------------------------------------------
__global__ __launch_bounds__(256) void k_nms_out(
    const unsigned long long* __restrict__ rowNZ,
    const float* __restrict__ bev,
    const float* __restrict__ props,
    const float* __restrict__ selsc,
    float* __restrict__ out)
{
    const int b = blockIdx.x;
    const int t = threadIdx.x;
    __shared__ float4 sbev[1024];
    __shared__ float sarea[1024];
    __shared__ unsigned long long keepW[16];
    __shared__ int wbase[16];
    __shared__ int sh_n;

    const float4* gb = (const float4*)(bev + (((size_t)b << 10) * 4));
    for (int i = t; i < 1024; i += 256) {
        float4 v = gb[i];
        sbev[i] = v;
        sarea[i] = (v.z - v.x) * (v.w - v.y);
    }
    __syncthreads();

    if (t < 64) {           // wave 0 does the (mostly trivial) serial pass
        const int lane = t;
        unsigned long long remv = 0ull;
        unsigned long long summ = (lane < 16) ? rowNZ[b * 16 + lane] : 0ull;
        for (int w = 0; w < 16; ++w) {
            unsigned long long rw = __shfl(remv, w);
            unsigned long long nz = __shfl(summ, w);
            unsigned long long keepw = ~rw;
            unsigned long long cand = nz & keepw;
            while (cand) {
                int bidx = __ffsll((long long)cand) - 1;
                cand &= cand - 1ull;
                if ((keepw >> bidx) & 1ull) {
                    const int i = (w << 6) + bidx;
                    const float4 bi = sbev[i];
                    const float ai = sarea[i];
                    unsigned long long row = 0ull;
#pragma unroll
                    for (int c = 0; c < 16; ++c) {
                        int j = (c << 6) + lane;
                        bool sup = false;
                        if (j > i) {
                            float4 bj = sbev[j];
                            float ltx = fmaxf(bi.x, bj.x), lty = fmaxf(bi.y, bj.y);
                            float rbx = fminf(bi.z, bj.z), rby = fminf(bi.w, bj.w);
                            float w0 = fmaxf(rbx - ltx, 0.f), h0 = fmaxf(rby - lty, 0.f);
                            float inter = w0 * h0;
                            float iou = inter / (ai + sarea[j] - inter + 1e-8f);
                            sup = iou > 0.85f;
                        }
                        unsigned long long word = __ballot(sup);
                        if (lane == c) row = word;
                    }
                    remv |= row;
                    unsigned long long roww = __shfl(row, w);
                    keepw &= ~roww;
                    cand  &= ~roww;
                }
            }
            if (lane == 0) keepW[w] = keepw;
        }
    }
    __syncthreads();

    if (t < 16) wbase[t] = (int)__popcll(keepW[t]);
    __syncthreads();
    if (t == 0) {
        int acc = 0;
        for (int w = 0; w < 16; ++w) { int c = wbase[w]; wbase[w] = acc; acc += c; }
        sh_n = acc;
    }
    __syncthreads();

    const int nk = sh_n;
    const int n = nk < KOUT ? nk : KOUT;
    const float* pb = props + (((size_t)b << 10) * 8);
    const float* scb = selsc + ((size_t)b << 10);
    float* ob = out + (size_t)b * KOUT * 7;
    float* os = out + (size_t)NB * KOUT * 7 + (size_t)b * KOUT;

    for (int i = t; i < 1024; i += 256) {
        const int w = i >> 6, bit = i & 63;
        unsigned long long kw = keepW[w];
        if ((kw >> bit) & 1ull) {
            int r = wbase[w] + (int)__popcll(kw & ((1ull << bit) - 1ull));
            if (r < KOUT) {
#pragma unroll
                for (int c = 0; c < 7; ++c) ob[r * 7 + c] = pb[i * 8 + c];
                os[r] = scb[i];
            }
        }
    }
    // zero unfilled slots (harness poisons d_out)
    {
        int r = t;
        if (r < KOUT && r >= n) {
#pragma unroll
            for (int c = 0; c < 7; ++c) ob[r * 7 + c] = 0.f;
            os[r] = 0.f;
        }
    }
}

// ---------------------------------------------------------------------------
extern "C" void kernel_launch(void* const* d_in, const int* in_sizes, int n_in,
                              void* d_out, int out_size, void* d_ws, size_t ws_size,
                              hipStream_t stream) {
    const float* scores = (const float*)d_in[0];
    const float* reg    = (const float*)d_in[1];
    const float* xyz    = (const float*)d_in[2];
    const float* msz    = (const float*)d_in[3];
    float* out = (float*)d_out;

    char* ws = (char*)d_ws;
    float* props = (float*)ws;                                    // 16*1024*8*4 = 512 KiB
    float* bev   = (float*)(ws + 524288);                         // 16*1024*4*4 = 256 KiB
    float* selsc = (float*)(ws + 524288 + 262144);                // 16*1024*4   =  64 KiB
    unsigned long long* rowNZ =
        (unsigned long long*)(ws + 524288 + 262144 + 65536);      // 16*16*8     =   2 KiB

    k_select_decode<<<dim3(NB), dim3(1024), 0, stream>>>(scores, reg, xyz, msz,
                                                         props, bev, selsc);
    k_overlap_flags<<<dim3(NB * 16), dim3(512), 0, stream>>>(bev, rowNZ);
    k_nms_out<<<dim3(NB), dim3(256), 0, stream>>>(rowNZ, bev, props, selsc, out);
}

// Round 5
// 49.978 us; speedup vs baseline: 28.7349x; 1.2611x over previous
//
#include <hip/hip_runtime.h>
#include <stdint.h>

// Problem constants (from reference)
#define NB 16
#define NP 16384
#define NC 76
#define KSEL 1024
#define KOUT 256

// ws layout (bytes)
#define WS_PROPS   0u         // 16*1024*8*4 = 524288
#define WS_BEV     524288u    // 16*1024*4*4 = 262144
#define WS_SELSC   786432u    // 16*1024*4   =  65536
#define WS_ROWNZ   851968u    // 16*16*8     =   2048
#define WS_KEYSEL  854016u    // 16*1024*8   = 131072

// ---------------------------------------------------------------------------
// Kernel 1: per-batch top-1024 selection. 4-pass radix select (12/12/12/10-bit
// digits) over composite key (mangled_score << 14) | (16383 - idx); writes the
// 1024 winner keys (unordered) to ws. One block (1024 thr) per batch.
// ---------------------------------------------------------------------------
__global__ __launch_bounds__(1024, 1) void k_select(
    const float* __restrict__ scores,       // [B][N]
    uint64_t* __restrict__ keysel)          // [B][1024]
{
    const int b = blockIdx.x;
    const int t = threadIdx.x;
    const int lane = t & 63;
    const int wave = t >> 6;

    const float* sb = scores + (size_t)b * NP;
    const float4* sb4 = (const float4*)sb;

    // 16 keys/thread, contiguous 16-score chunk per thread (4x float4).
    uint64_t key[16];
#pragma unroll
    for (int q = 0; q < 4; ++q) {
        float4 v = sb4[(t << 2) + q];
        const float vs[4] = {v.x, v.y, v.z, v.w};
#pragma unroll
        for (int e = 0; e < 4; ++e) {
            int i = (t << 4) + (q << 2) + e;
            uint32_t u = __float_as_uint(vs[e]);
            u ^= (u & 0x80000000u) ? 0xFFFFFFFFu : 0x80000000u;
            key[(q << 2) + e] = ((uint64_t)u << 14) | (uint64_t)(16383 - i);
        }
    }

    __shared__ unsigned int hist[4096];
    __shared__ unsigned int wtot[16];
    __shared__ uint64_t sh_prefix;
    __shared__ unsigned int sh_remaining;
    __shared__ unsigned int selcnt;
    if (t == 0) { sh_prefix = 0ull; sh_remaining = KSEL; selcnt = 0u; }

    const int shifts[4] = {34, 22, 10, 0};
    const int dbits [4] = {12, 12, 12, 10};

    uint64_t prefix = 0ull;
    for (int pass = 0; pass < 4; ++pass) {
        const int shift = shifts[pass];
        const int nb    = dbits[pass];
        const unsigned dmask = (1u << nb) - 1u;
        // zero histogram (4 words/thread)
#pragma unroll
        for (int q = 0; q < 4; ++q) hist[(q << 10) + t] = 0u;
        __syncthreads();
#pragma unroll
        for (int k = 0; k < 16; ++k) {
            uint64_t kk = key[k];
            if ((kk >> (shift + nb)) == (prefix >> (shift + nb)))
                atomicAdd(&hist[(unsigned)(kk >> shift) & dmask], 1u);
        }
        __syncthreads();
        // suffix scan: thread t owns bins 4t..4t+3
        const unsigned c0 = hist[(t << 2) + 0];
        const unsigned c1 = hist[(t << 2) + 1];
        const unsigned c2 = hist[(t << 2) + 2];
        const unsigned c3 = hist[(t << 2) + 3];
        const unsigned s = c0 + c1 + c2 + c3;
        unsigned v = s;
#pragma unroll
        for (int o = 1; o < 64; o <<= 1) {
            unsigned u = __shfl_down(v, o);
            v += (lane + o < 64) ? u : 0u;
        }
        if (lane == 0) wtot[wave] = v;       // wave-inclusive suffix total
        __syncthreads();
        unsigned add = 0;
#pragma unroll
        for (int w = 0; w < 16; ++w) if (w > wave) add += wtot[w];
        const unsigned Wt   = v + add;       // suffix from thread t (inclusive)
        const unsigned base = Wt - s;        // suffix from bin 4t+4
        const unsigned S3 = base + c3;
        const unsigned S2 = S3 + c2;
        const unsigned S1 = S2 + c1;
        const unsigned S0 = S1 + c0;
        const unsigned rem = sh_remaining;   // everyone reads rem
        int dig = -1; unsigned nrem = 0;
        if      (S3 >= rem && base < rem) { dig = (t << 2) + 3; nrem = rem - base; }
        else if (S2 >= rem && S3  < rem)  { dig = (t << 2) + 2; nrem = rem - S3; }
        else if (S1 >= rem && S2  < rem)  { dig = (t << 2) + 1; nrem = rem - S2; }
        else if (S0 >= rem && S1  < rem)  { dig = (t << 2) + 0; nrem = rem - S1; }
        __syncthreads();                     // all rem reads done before write
        if (dig >= 0) {                      // unique boundary thread
            sh_prefix |= ((uint64_t)(unsigned)dig) << shift;
            sh_remaining = nrem;
        }
        __syncthreads();
        prefix = sh_prefix;
    }
    const uint64_t T = prefix;   // exact 1024th-largest key (all keys distinct)

    // compact the exactly-1024 winners straight to ws (wave-aggregated)
    uint64_t* kout = keysel + ((size_t)b << 10);
#pragma unroll
    for (int k = 0; k < 16; ++k) {
        bool p = key[k] >= T;
        unsigned long long m = __ballot(p);
        if (m) {
            unsigned int base2;
            if (lane == 0) base2 = atomicAdd(&selcnt, (unsigned)__popcll(m));
            base2 = __shfl(base2, 0);
            if (p) kout[base2 + (unsigned)__popcll(m & ((1ull << lane) - 1ull))] = key[k];
        }
    }
}

// ---------------------------------------------------------------------------
// Kernel 1b: rank-by-counting + decode + BEV. 8 blocks/batch x 128 thr.
// Each thread ranks its key among the batch's 1024 (LDS broadcast loop),
// then decodes that proposal and writes props/bev/selsc at its rank.
// ---------------------------------------------------------------------------
__global__ __launch_bounds__(128) void k_decode(
    const float* __restrict__ scores,   // [B][N]
    const float* __restrict__ reg,      // [B][N][76]
    const float* __restrict__ xyz,      // [B][N][3]
    const float* __restrict__ msz,      // [3]
    const uint64_t* __restrict__ keysel,// [B][1024]
    float* __restrict__ props,          // [B][1024][8]
    float* __restrict__ bev,            // [B][1024][4]
    float* __restrict__ selsc)          // [B][1024]
{
    const int b = blockIdx.x >> 3;
    const int r = blockIdx.x & 7;       // chunk of 128 keys
    const int t = threadIdx.x;

    __shared__ uint64_t sk[1024];
    const uint64_t* kin = keysel + ((size_t)b << 10);
    for (int q = t; q < 1024; q += 128) sk[q] = kin[q];
    __syncthreads();

    const uint64_t kk = sk[(r << 7) + t];
    int rank = 0;
#pragma unroll 16
    for (int j = 0; j < 1024; ++j) rank += (sk[j] > kk) ? 1 : 0;

    const int idx = 16383 - (int)(kk & 16383ull);
    const float sc = scores[(size_t)b * NP + idx];
    const float* rr = reg + ((size_t)b * NP + idx) * NC;
    const float* xr = xyz + ((size_t)b * NP + idx) * 3;
    const float4* rr4 = (const float4*)rr;   // rows are 16B-aligned (76*4=304)

    float4 R0 = rr4[0], R1 = rr4[1], R2 = rr4[2];       // x bins 0..11
    float4 R3 = rr4[3], R4 = rr4[4], R5 = rr4[5];       // z bins 12..23
    float4 R12 = rr4[12], R13 = rr4[13], R14 = rr4[14]; // 48..59
    float r60 = rr[60];
    float4 R18 = rr4[18];                               // 72..75

    float best; int bj;
    {
        const float vx[12] = {R0.x,R0.y,R0.z,R0.w,R1.x,R1.y,R1.z,R1.w,R2.x,R2.y,R2.z,R2.w};
        best = vx[0]; bj = 0;
#pragma unroll
        for (int j = 1; j < 12; ++j) if (vx[j] > best) { best = vx[j]; bj = j; }
    }
    const int xbin = bj;
    {
        const float vz[12] = {R3.x,R3.y,R3.z,R3.w,R4.x,R4.y,R4.z,R4.w,R5.x,R5.y,R5.z,R5.w};
        best = vz[0]; bj = 0;
#pragma unroll
        for (int j = 1; j < 12; ++j) if (vz[j] > best) { best = vz[j]; bj = j; }
    }
    const int zbin = bj;
    {
        const float vr[12] = {R12.y,R12.z,R12.w,R13.x,R13.y,R13.z,R13.w,R14.x,R14.y,R14.z,R14.w,r60};
        best = vr[0]; bj = 0;
#pragma unroll
        for (int j = 1; j < 12; ++j) if (vr[j] > best) { best = vr[j]; bj = j; }
    }
    const int rybin = bj;

    const float xres = rr[24 + xbin];    // dynamic gathers stay in global
    const float zres = rr[36 + zbin];
    const float ryres = rr[61 + rybin];

    float posx = ((float)xbin * 0.5f + 0.25f - 3.0f) + xres * 0.5f;
    float posz = ((float)zbin * 0.5f + 0.25f - 3.0f) + zres * 0.5f;
    float posy = xr[1] + R12.x;          // rr[48]

    const float apc   = 0.5235987755982988f;   // 2*pi/12
    const float apch  = 0.2617993877991494f;   // apc/2
    const float twopi = 6.283185307179586f;
    const float fpi   = 3.141592653589793f;
    float ry = (float)rybin * apc + ryres * apch;
    ry = fmodf(ry, twopi);
    if (ry < 0.f) ry += twopi;
    if (ry > fpi) ry -= twopi;

    const float a0 = msz[0], a1 = msz[1], a2 = msz[2];
    const float h = R18.y * a0 + a0;     // rr[73..75]
    const float w = R18.z * a1 + a1;
    const float l = R18.w * a2 + a2;
    posx += xr[0];
    posz += xr[2];
    posy += h * 0.5f;                    // props[:,1] += h/2

    const size_t o = ((size_t)b << 10) | (size_t)rank;
    float* pp = props + o * 8;
    pp[0] = posx; pp[1] = posy; pp[2] = posz; pp[3] = h; pp[4] = w; pp[5] = l; pp[6] = ry;
    const float hl = l * 0.5f, hw = w * 0.5f;
    float* bb = bev + o * 4;
    bb[0] = posx - hl; bb[1] = posz - hw; bb[2] = posx + hl; bb[3] = posz + hw;
    selsc[o] = sc;
}

// ---------------------------------------------------------------------------
// Kernel 2: mark rows that suppress anything (loose threshold -> superset,
// exact decision recomputed in kernel 3). One block per (batch, 64-row word).
// Divide-free IoU test WITH sign guard (areas can be negative; for D<=0 the
// reference iou = inter/D <= 0 never suppresses).
// ---------------------------------------------------------------------------
__global__ __launch_bounds__(512) void k_overlap_flags(
    const float* __restrict__ bev,
    unsigned long long* __restrict__ rowNZ)
{
    const int b  = blockIdx.x >> 4;
    const int ic = blockIdx.x & 15;      // i-word index (rows ic*64 .. ic*64+63)
    const int t = threadIdx.x;
    const int lane = t & 63;
    const int wv = t >> 6;               // 0..7 -> j window [wv*128, wv*128+128)

    __shared__ float4 sbev[1024];
    __shared__ float sarea[1024];
    __shared__ unsigned long long sword;
    if (t == 0) sword = 0ull;

    const float4* gb = (const float4*)(bev + (((size_t)b << 10) * 4));
    for (int i = t; i < 1024; i += 512) {
        float4 v = gb[i];
        sbev[i] = v;
        sarea[i] = (v.z - v.x) * (v.w - v.y);
    }
    __syncthreads();

    const int i = (ic << 6) + lane;
    const float4 bi = sbev[i];
    const float aie = sarea[i] + 1e-8f;  // ai + eps

    bool any = false;
    const int j0 = wv << 7;
    if (j0 + 127 > i) {                  // wave-uniform skip for windows below i-word
#pragma unroll 4
        for (int j = j0; j < j0 + 128; ++j) {
            float4 bj = sbev[j];
            float ltx = fmaxf(bi.x, bj.x), lty = fmaxf(bi.y, bj.y);
            float rbx = fminf(bi.z, bj.z), rby = fminf(bi.w, bj.w);
            float w0 = fmaxf(rbx - ltx, 0.f), h0 = fmaxf(rby - lty, 0.f);
            float inter = w0 * h0;
            float sum = aie + sarea[j];          // ai + aj + eps
            // iou > 0.8495  <=>  (sum - inter > 0) && inter*1.8495 > 0.8495*sum
            any |= (j > i) & (sum > inter) & (inter * 1.8495f > 0.8495f * sum);
        }
    }
    unsigned long long m = __ballot(any);
    if (lane == 0 && m) atomicOr(&sword, m);
    __syncthreads();
    if (t == 0) rowNZ[b * 16 + ic] = sword;   // sole owner of this word
}

// ---------------------------------------------------------------------------
// Kernel 3: greedy NMS propagation (word-blocked; exact 0.85 threshold,
// rows rebuilt on demand via ballots) + output scatter. 1 block per batch.
// ---------------------------------------------------------------------------
__global__ __launch_bounds__(256) void k_nms_out(
    const unsigned long long* __restrict__ rowNZ,
    const float* __restrict__ bev,
    const float* __restrict__ props,
    const float* __restrict__ selsc,
    float* __restrict__ out)
{
    const int b = blockIdx.x;
    const int t = threadIdx.x;
    __shared__ float4 sbev[1024];
    __shared__ float sarea[1024];
    __shared__ unsigned long long keepW[16];
    __shared__ int wbase[16];
    __shared__ int sh_n;

    const float4* gb = (const float4*)(bev + (((size_t)b << 10) * 4));
    for (int i = t; i < 1024; i += 256) {
        float4 v = gb[i];
        sbev[i] = v;
        sarea[i] = (v.z - v.x) * (v.w - v.y);
    }
    __syncthreads();

    if (t < 64) {           // wave 0 does the (mostly trivial) serial pass
        const int lane = t;
        unsigned long long remv = 0ull;
        unsigned long long summ = (lane < 16) ? rowNZ[b * 16 + lane] : 0ull;
        for (int w = 0; w < 16; ++w) {
            unsigned long long rw = __shfl(remv, w);
            unsigned long long nz = __shfl(summ, w);
            unsigned long long keepw = ~rw;
            unsigned long long cand = nz & keepw;
            while (cand) {
                int bidx = __ffsll((long long)cand) - 1;
                cand &= cand - 1ull;
                if ((keepw >> bidx) & 1ull) {
                    const int i = (w << 6) + bidx;
                    const float4 bi = sbev[i];
                    const float ai = sarea[i];
                    unsigned long long row = 0ull;
#pragma unroll
                    for (int c = 0; c < 16; ++c) {
                        int j = (c << 6) + lane;
                        bool sup = false;
                        if (j > i) {
                            float4 bj = sbev[j];
                            float ltx = fmaxf(bi.x, bj.x), lty = fmaxf(bi.y, bj.y);
                            float rbx = fminf(bi.z, bj.z), rby = fminf(bi.w, bj.w);
                            float w0 = fmaxf(rbx - ltx, 0.f), h0 = fmaxf(rby - lty, 0.f);
                            float inter = w0 * h0;
                            float iou = inter / (ai + sarea[j] - inter + 1e-8f);
                            sup = iou > 0.85f;
                        }
                        unsigned long long word = __ballot(sup);
                        if (lane == c) row = word;
                    }
                    remv |= row;
                    unsigned long long roww = __shfl(row, w);
                    keepw &= ~roww;
                    cand  &= ~roww;
                }
            }
            if (lane == 0) keepW[w] = keepw;
        }
    }
    __syncthreads();

    if (t < 16) wbase[t] = (int)__popcll(keepW[t]);
    __syncthreads();
    if (t == 0) {
        int acc = 0;
        for (int w = 0; w < 16; ++w) { int c = wbase[w]; wbase[w] = acc; acc += c; }
        sh_n = acc;
    }
    __syncthreads();

    const int nk = sh_n;
    const int n = nk < KOUT ? nk : KOUT;
    const float* pb = props + (((size_t)b << 10) * 8);
    const float* scb = selsc + ((size_t)b << 10);
    float* ob = out + (size_t)b * KOUT * 7;
    float* os = out + (size_t)NB * KOUT * 7 + (size_t)b * KOUT;

    for (int i = t; i < 1024; i += 256) {
        const int w = i >> 6, bit = i & 63;
        unsigned long long kw = keepW[w];
        if ((kw >> bit) & 1ull) {
            int r = wbase[w] + (int)__popcll(kw & ((1ull << bit) - 1ull));
            if (r < KOUT) {
#pragma unroll
                for (int c = 0; c < 7; ++c) ob[r * 7 + c] = pb[i * 8 + c];
                os[r] = scb[i];
            }
        }
    }
    // zero unfilled slots (harness poisons d_out)
    {
        int r = t;
        if (r < KOUT && r >= n) {
#pragma unroll
            for (int c = 0; c < 7; ++c) ob[r * 7 + c] = 0.f;
            os[r] = 0.f;
        }
    }
}

// ---------------------------------------------------------------------------
extern "C" void kernel_launch(void* const* d_in, const int* in_sizes, int n_in,
                              void* d_out, int out_size, void* d_ws, size_t ws_size,
                              hipStream_t stream) {
    const float* scores = (const float*)d_in[0];
    const float* reg    = (const float*)d_in[1];
    const float* xyz    = (const float*)d_in[2];
    const float* msz    = (const float*)d_in[3];
    float* out = (float*)d_out;

    char* ws = (char*)d_ws;
    float* props = (float*)(ws + WS_PROPS);
    float* bev   = (float*)(ws + WS_BEV);
    float* selsc = (float*)(ws + WS_SELSC);
    unsigned long long* rowNZ = (unsigned long long*)(ws + WS_ROWNZ);
    uint64_t* keysel = (uint64_t*)(ws + WS_KEYSEL);

    k_select<<<dim3(NB), dim3(1024), 0, stream>>>(scores, keysel);
    k_decode<<<dim3(NB * 8), dim3(128), 0, stream>>>(scores, reg, xyz, msz,
                                                     keysel, props, bev, selsc);
    k_overlap_flags<<<dim3(NB * 16), dim3(512), 0, stream>>>(bev, rowNZ);
    k_nms_out<<<dim3(NB), dim3(256), 0, stream>>>(rowNZ, bev, props, selsc, out);
}